// Round 9
// baseline (8297.327 us; speedup 1.0000x reference)
//
#include <hip/hip_runtime.h>
#include <hip/hip_cooperative_groups.h>
#include <math.h>

namespace cg = cooperative_groups;

#define N_NODES 100000
#define N_EDGES 1600000
#define IN_C 128
#define HID_C 128
#define OUT_C 64
#define NLAYERS 4
#define KSTEPS 10
#define ALPHA 0.1f
#define LN_EPS 1e-5f

#define SCAN_N (N_NODES + 1)
#define SCAN_BLOCKS ((SCAN_N + 1023) / 1024)     // 98
#define EP_CAP 2400000                            // 1.6M edges + <=7 pad/node
#define PROP_GRID 1024                            // 4 blocks/CU -> coop co-resident

__device__ __forceinline__ float gelu_exact(float x) {
    return 0.5f * x * (1.0f + erff(x * 0.70710678118654752f));
}
__device__ __forceinline__ unsigned pack_bf16_rne(float a, float b) {
    unsigned ua = __float_as_uint(a);
    unsigned ub = __float_as_uint(b);
    ua = (ua + 0x7fffu + ((ua >> 16) & 1u)) >> 16;
    ub = (ub + 0x7fffu + ((ub >> 16) & 1u)) >> 16;
    return (ub << 16) | ua;
}
__device__ __forceinline__ float bf_lo(unsigned d) { return __uint_as_float(d << 16); }
__device__ __forceinline__ float bf_hi(unsigned d) { return __uint_as_float(d & 0xffff0000u); }

// ---------------------------------------------------------------------------
// CSR build: count in-degree per dst
__global__ void count_k(const int* __restrict__ dst, int* __restrict__ counts) {
    int e = blockIdx.x * blockDim.x + threadIdx.x;
    if (e < N_EDGES) atomicAdd(&counts[dst[e]], 1);
}

// scan1: per-block sums of padded (x8) counts
__global__ __launch_bounds__(1024) void scan1_k(const int* __restrict__ counts,
                                                int* __restrict__ bsum) {
    __shared__ int s[1024];
    int i = blockIdx.x * 1024 + threadIdx.x;
    int c = 0;
    if (i < N_NODES) c = (counts[i] + 7) & ~7;
    s[threadIdx.x] = c;
    __syncthreads();
    for (int off = 512; off; off >>= 1) {
        if (threadIdx.x < off) s[threadIdx.x] += s[threadIdx.x + off];
        __syncthreads();
    }
    if (threadIdx.x == 0) bsum[blockIdx.x] = s[0];
}

// scan2: exclusive scan of the 98 block sums
__global__ void scan2_k(int* __restrict__ bsum) {
    __shared__ int s[128];
    int t = threadIdx.x;
    s[t] = (t < SCAN_BLOCKS) ? bsum[t] : 0;
    __syncthreads();
    for (int off = 1; off < 128; off <<= 1) {
        int v = (t >= off) ? s[t - off] : 0;
        __syncthreads();
        s[t] += v;
        __syncthreads();
    }
    if (t < SCAN_BLOCKS) bsum[t] = (t == 0) ? 0 : s[t - 1];
}

// scan3: per-block exclusive scan + block offset -> row_off / fill_pos
__global__ __launch_bounds__(1024) void scan3_k(const int* __restrict__ counts,
                                                const int* __restrict__ bsum,
                                                int* __restrict__ row_off,
                                                int* __restrict__ fill_pos) {
    __shared__ int s[1024];
    int i = blockIdx.x * 1024 + threadIdx.x;
    int c = 0;
    if (i < N_NODES) c = (counts[i] + 7) & ~7;
    s[threadIdx.x] = c;
    __syncthreads();
    for (int off = 1; off < 1024; off <<= 1) {
        int v = (threadIdx.x >= off) ? s[threadIdx.x - off] : 0;
        __syncthreads();
        s[threadIdx.x] += v;
        __syncthreads();
    }
    if (i <= N_NODES) {
        int excl = s[threadIdx.x] - c + bsum[blockIdx.x];
        row_off[i] = excl;
        fill_pos[i] = excl;
    }
}

// Bucket edges by dst; pack (src*64 [dword row offset], (1-alpha)*w fp32).
// Pad slots stay (0,0.0f) from the ep memset -> gather row 0 (cache-hot) * 0.
__global__ void bucket_k(const int* __restrict__ src, const int* __restrict__ dst,
                         const float* __restrict__ w,
                         int* __restrict__ fill_pos, int2* __restrict__ ep) {
    int e = blockIdx.x * blockDim.x + threadIdx.x;
    if (e >= N_EDGES) return;
    int d = dst[e];
    int pos = atomicAdd(&fill_pos[d], 1);
    float ws = (1.0f - ALPHA) * w[e];
    ep[pos] = make_int2(src[e] << 6, __float_as_int(ws));
}

// ---------------------------------------------------------------------------
// Encoder: H(bf16) = gelu(LN(x @ Wenc^T)).  (proven R5 structure)
__global__ __launch_bounds__(1024) void encoder_k(
        const float* __restrict__ x, const float* __restrict__ Wenc,
        const float* __restrict__ gamma, const float* __restrict__ beta,
        unsigned* __restrict__ H) {
    __shared__ float WT[IN_C * 130];
    __shared__ float XS[16][512];
    for (int i = threadIdx.x; i < IN_C * HID_C; i += 1024) {
        int c = i >> 7, k = i & 127;
        WT[k * 130 + c] = Wenc[i];
    }
    __syncthreads();
    int lane = threadIdx.x & 63;
    int wid  = threadIdx.x >> 6;
    const float2* WT2 = (const float2*)WT;
    float2 gb = ((const float2*)gamma)[lane];
    float2 bb = ((const float2*)beta)[lane];
    int wstride = gridDim.x * 16;
    float* xs = XS[wid];
    for (int grp = blockIdx.x * 16 + wid; grp * 4 < N_NODES; grp += wstride) {
        int r0 = grp * 4;
        const float4* xr = (const float4*)(x + (size_t)r0 * IN_C);
        ((float4*)xs)[lane]      = xr[lane];
        ((float4*)xs)[64 + lane] = xr[64 + lane];
        __builtin_amdgcn_wave_barrier();
        float a0x = 0, a0y = 0, a1x = 0, a1y = 0;
        float a2x = 0, a2y = 0, a3x = 0, a3y = 0;
        const float4* xs4 = (const float4*)xs;
#pragma unroll 4
        for (int k4 = 0; k4 < 32; ++k4) {
            float4 xv0 = xs4[k4];
            float4 xv1 = xs4[32 + k4];
            float4 xv2 = xs4[64 + k4];
            float4 xv3 = xs4[96 + k4];
            int k = k4 * 4;
            float2 w0 = WT2[(k + 0) * 65 + lane];
            float2 w1 = WT2[(k + 1) * 65 + lane];
            float2 w2 = WT2[(k + 2) * 65 + lane];
            float2 w3 = WT2[(k + 3) * 65 + lane];
#define ENC_ROW(ax, ay, xv)                                      \
            ax = fmaf(xv.x, w0.x, ax); ay = fmaf(xv.x, w0.y, ay); \
            ax = fmaf(xv.y, w1.x, ax); ay = fmaf(xv.y, w1.y, ay); \
            ax = fmaf(xv.z, w2.x, ax); ay = fmaf(xv.z, w2.y, ay); \
            ax = fmaf(xv.w, w3.x, ax); ay = fmaf(xv.w, w3.y, ay);
            ENC_ROW(a0x, a0y, xv0)
            ENC_ROW(a1x, a1y, xv1)
            ENC_ROW(a2x, a2y, xv2)
            ENC_ROW(a3x, a3y, xv3)
#undef ENC_ROW
        }
        __builtin_amdgcn_wave_barrier();
#define ENC_EPI(ax, ay, row)                                               \
        {                                                                   \
            float sum = ax + ay;                                            \
            for (int off = 32; off; off >>= 1) sum += __shfl_xor(sum, off); \
            float mu = sum * (1.0f / 128.0f);                               \
            float d0 = ax - mu, d1 = ay - mu;                               \
            float vs = d0 * d0 + d1 * d1;                                   \
            for (int off = 32; off; off >>= 1) vs += __shfl_xor(vs, off);   \
            float inv = rsqrtf(vs * (1.0f / 128.0f) + LN_EPS);              \
            float o0 = gelu_exact(gb.x * d0 * inv + bb.x);                  \
            float o1 = gelu_exact(gb.y * d1 * inv + bb.y);                  \
            H[(size_t)(row)*64 + lane] = pack_bf16_rne(o0, o1);             \
        }
        ENC_EPI(a0x, a0y, r0)
        ENC_EPI(a1x, a1y, r0 + 1)
        ENC_EPI(a2x, a2y, r0 + 2)
        ENC_EPI(a3x, a3y, r0 + 3)
#undef ENC_EPI
    }
}

// ---------------------------------------------------------------------------
// ALL 40 APPNP steps in one persistent cooperative kernel. Inner engine = R5's
// proven wave-per-node pull (64-edge coop window, 8 gathers of 256 B rows in
// flight, x8-padded degrees). grid.sync() between steps replaces 40 launches.
// Safety: each node's x0/H row is read only by its owning wave before that
// wave writes it; cross-node reads only touch zin (!= zout every step).
__global__ __launch_bounds__(256, 4) void prop_all_k(
        const int* __restrict__ row_off, const int2* __restrict__ ep,
        unsigned* __restrict__ H, unsigned* __restrict__ ZA,
        unsigned* __restrict__ ZB,
        const float* __restrict__ gamma, const float* __restrict__ beta) {
    cg::grid_group grid = cg::this_grid();
    int lane = threadIdx.x & 63;
    int wave0 = (blockIdx.x * 256 + threadIdx.x) >> 6;
    const int NW = (PROP_GRID * 256) >> 6;                 // 4096 waves
    float2 gb = ((const float2*)gamma)[lane];
    float2 bb = ((const float2*)beta)[lane];
    unsigned* bufs[2] = {ZA, ZB};
    for (int l = 0; l < NLAYERS; ++l) {
        const unsigned* zin = H;                           // x0 = H (layer input)
        for (int k = 0; k < KSTEPS; ++k) {
            int last = (k == KSTEPS - 1);
            unsigned* zout = last ? H : bufs[k & 1];
            for (int gw = wave0; gw < N_NODES; gw += NW) {
                int s0 = row_off[gw];
                int s1 = row_off[gw + 1];                  // padded degree (x8)
                float sx = 0.f, sy = 0.f;
                for (int base = s0; base < s1; base += 64) {
                    int cnt = min(64, s1 - base);          // multiple of 8
                    int2 p = make_int2(0, 0);
                    if (lane < cnt) p = ep[base + lane];
                    for (int j = 0; j < cnt; j += 8) {
                        int   o0 = __shfl(p.x, j + 0); float w0 = __int_as_float(__shfl(p.y, j + 0));
                        int   o1 = __shfl(p.x, j + 1); float w1 = __int_as_float(__shfl(p.y, j + 1));
                        int   o2 = __shfl(p.x, j + 2); float w2 = __int_as_float(__shfl(p.y, j + 2));
                        int   o3 = __shfl(p.x, j + 3); float w3 = __int_as_float(__shfl(p.y, j + 3));
                        int   o4 = __shfl(p.x, j + 4); float w4 = __int_as_float(__shfl(p.y, j + 4));
                        int   o5 = __shfl(p.x, j + 5); float w5 = __int_as_float(__shfl(p.y, j + 5));
                        int   o6 = __shfl(p.x, j + 6); float w6 = __int_as_float(__shfl(p.y, j + 6));
                        int   o7 = __shfl(p.x, j + 7); float w7 = __int_as_float(__shfl(p.y, j + 7));
                        unsigned d0 = zin[o0 + lane];
                        unsigned d1 = zin[o1 + lane];
                        unsigned d2 = zin[o2 + lane];
                        unsigned d3 = zin[o3 + lane];
                        unsigned d4 = zin[o4 + lane];
                        unsigned d5 = zin[o5 + lane];
                        unsigned d6 = zin[o6 + lane];
                        unsigned d7 = zin[o7 + lane];
                        sx = fmaf(w0, bf_lo(d0), sx); sy = fmaf(w0, bf_hi(d0), sy);
                        sx = fmaf(w1, bf_lo(d1), sx); sy = fmaf(w1, bf_hi(d1), sy);
                        sx = fmaf(w2, bf_lo(d2), sx); sy = fmaf(w2, bf_hi(d2), sy);
                        sx = fmaf(w3, bf_lo(d3), sx); sy = fmaf(w3, bf_hi(d3), sy);
                        sx = fmaf(w4, bf_lo(d4), sx); sy = fmaf(w4, bf_hi(d4), sy);
                        sx = fmaf(w5, bf_lo(d5), sx); sy = fmaf(w5, bf_hi(d5), sy);
                        sx = fmaf(w6, bf_lo(d6), sx); sy = fmaf(w6, bf_hi(d6), sy);
                        sx = fmaf(w7, bf_lo(d7), sx); sy = fmaf(w7, bf_hi(d7), sy);
                    }
                }
                unsigned xd = H[(size_t)gw * 64 + lane];   // x0 row (own node)
                float zx = fmaf(ALPHA, bf_lo(xd), sx);
                float zy = fmaf(ALPHA, bf_hi(xd), sy);
                unsigned od;
                if (last) {
                    float h0 = gelu_exact(zx);
                    float h1 = gelu_exact(zy);
                    float sum = h0 + h1;
                    for (int off = 32; off; off >>= 1) sum += __shfl_xor(sum, off);
                    float mu = sum * (1.0f / 128.0f);
                    float d0 = h0 - mu, d1 = h1 - mu;
                    float vs = d0 * d0 + d1 * d1;
                    for (int off = 32; off; off >>= 1) vs += __shfl_xor(vs, off);
                    float inv = rsqrtf(vs * (1.0f / 128.0f) + LN_EPS);
                    od = pack_bf16_rne(gb.x * d0 * inv + bb.x, gb.y * d1 * inv + bb.y);
                } else {
                    od = pack_bf16_rne(zx, zy);
                }
                zout[(size_t)gw * 64 + lane] = od;
            }
            grid.sync();
            zin = zout;
        }
    }
}

// ---------------------------------------------------------------------------
// Decoder: out(fp32) = H(bf16) @ Wdec^T -> [N, 64].  (proven R5 structure)
__global__ __launch_bounds__(1024) void decoder_k(
        const unsigned* __restrict__ H, const float* __restrict__ Wdec,
        float* __restrict__ out) {
    __shared__ float WT[HID_C * 65];
    __shared__ unsigned XS[16][256];
    for (int i = threadIdx.x; i < OUT_C * HID_C; i += 1024) {
        int o = i >> 7, k = i & 127;
        WT[k * 65 + o] = Wdec[i];
    }
    __syncthreads();
    int lane = threadIdx.x & 63;
    int wid  = threadIdx.x >> 6;
    int wstride = gridDim.x * 16;
    unsigned* xs = XS[wid];
    for (int grp = blockIdx.x * 16 + wid; grp * 4 < N_NODES; grp += wstride) {
        int r0 = grp * 4;
        const unsigned* hp = H + (size_t)r0 * 64;
        xs[lane]       = hp[lane];
        xs[64 + lane]  = hp[64 + lane];
        xs[128 + lane] = hp[128 + lane];
        xs[192 + lane] = hp[192 + lane];
        __builtin_amdgcn_wave_barrier();
        float a0 = 0, a1 = 0, a2 = 0, a3 = 0;
#pragma unroll 4
        for (int k2 = 0; k2 < 64; ++k2) {
            float w0 = WT[(2 * k2) * 65 + lane];
            float w1 = WT[(2 * k2 + 1) * 65 + lane];
            unsigned u0 = xs[k2];
            unsigned u1 = xs[64 + k2];
            unsigned u2 = xs[128 + k2];
            unsigned u3 = xs[192 + k2];
            a0 = fmaf(bf_lo(u0), w0, a0); a0 = fmaf(bf_hi(u0), w1, a0);
            a1 = fmaf(bf_lo(u1), w0, a1); a1 = fmaf(bf_hi(u1), w1, a1);
            a2 = fmaf(bf_lo(u2), w0, a2); a2 = fmaf(bf_hi(u2), w1, a2);
            a3 = fmaf(bf_lo(u3), w0, a3); a3 = fmaf(bf_hi(u3), w1, a3);
        }
        __builtin_amdgcn_wave_barrier();
        out[(size_t)r0 * OUT_C + lane]       = a0;
        out[(size_t)(r0 + 1) * OUT_C + lane] = a1;
        out[(size_t)(r0 + 2) * OUT_C + lane] = a2;
        out[(size_t)(r0 + 3) * OUT_C + lane] = a3;
    }
}

// ---------------------------------------------------------------------------
extern "C" void kernel_launch(void* const* d_in, const int* in_sizes, int n_in,
                              void* d_out, int out_size, void* d_ws, size_t ws_size,
                              hipStream_t stream) {
    const float* x     = (const float*)d_in[0];
    const int*   ei    = (const int*)d_in[1];
    const float* ew    = (const float*)d_in[2];
    const float* Wenc  = (const float*)d_in[3];
    const float* Wdec  = (const float*)d_in[4];
    const float* gamma = (const float*)d_in[5];
    const float* beta  = (const float*)d_in[6];
    float* out = (float*)d_out;

    const int* src = ei;
    const int* dst = ei + N_EDGES;

    char* p = (char*)d_ws;
    auto carve = [&](size_t bytes) -> void* {
        void* r = (void*)p;
        p += (bytes + 255) & ~(size_t)255;
        return r;
    };
    int*  counts  = (int*)carve(SCAN_N * sizeof(int));
    int*  fillpos = (int*)carve(SCAN_N * sizeof(int));
    int*  row_off = (int*)carve(SCAN_N * sizeof(int));
    int*  bsum    = (int*)carve(SCAN_BLOCKS * sizeof(int));
    int2* ep      = (int2*)carve((size_t)EP_CAP * sizeof(int2));
    unsigned* H  = (unsigned*)carve((size_t)N_NODES * 64 * sizeof(unsigned));
    unsigned* ZA = (unsigned*)carve((size_t)N_NODES * 64 * sizeof(unsigned));
    unsigned* ZB = (unsigned*)carve((size_t)N_NODES * 64 * sizeof(unsigned));

    // CSR build (per launch; deterministic work each call)
    hipMemsetAsync(counts, 0, SCAN_N * sizeof(int), stream);
    hipMemsetAsync(ep, 0, (size_t)EP_CAP * sizeof(int2), stream);  // pads -> (0,0)
    count_k<<<(N_EDGES + 255) / 256, 256, 0, stream>>>(dst, counts);
    scan1_k<<<SCAN_BLOCKS, 1024, 0, stream>>>(counts, bsum);
    scan2_k<<<1, 128, 0, stream>>>(bsum);
    scan3_k<<<SCAN_BLOCKS, 1024, 0, stream>>>(counts, bsum, row_off, fillpos);
    bucket_k<<<(N_EDGES + 255) / 256, 256, 0, stream>>>(src, dst, ew, fillpos, ep);

    // Encoder
    encoder_k<<<512, 1024, 0, stream>>>(x, Wenc, gamma, beta, H);

    // All 40 APPNP steps in one cooperative launch
    {
        const int* ro = row_off; const int2* epp = ep;
        unsigned *h = H, *za = ZA, *zb = ZB;
        const float *g = gamma, *b = beta;
        void* args[] = {(void*)&ro, (void*)&epp, (void*)&h, (void*)&za,
                        (void*)&zb, (void*)&g, (void*)&b};
        hipLaunchCooperativeKernel((void*)prop_all_k, dim3(PROP_GRID), dim3(256),
                                   args, 0, stream);
    }

    decoder_k<<<512, 1024, 0, stream>>>(H, Wdec, out);
}

// Round 10
// 2885.839 us; speedup vs baseline: 2.8752x; 2.8752x over previous
//
#include <hip/hip_runtime.h>
#include <math.h>

#define N_NODES 100000
#define N_EDGES 1600000
#define IN_C 128
#define HID_C 128
#define OUT_C 64
#define NLAYERS 4
#define KSTEPS 10
#define ALPHA 0.1f
#define LN_EPS 1e-5f

#define SCAN_N (N_NODES + 1)
#define SCAN_BLOCKS ((SCAN_N + 1023) / 1024)     // 98
#define EP_CAP 2400000                            // 1.6M edges + <=7 pad/node

__device__ __forceinline__ float gelu_exact(float x) {
    return 0.5f * x * (1.0f + erff(x * 0.70710678118654752f));
}
__device__ __forceinline__ unsigned pack_bf16_rne(float a, float b) {
    unsigned ua = __float_as_uint(a);
    unsigned ub = __float_as_uint(b);
    ua = (ua + 0x7fffu + ((ua >> 16) & 1u)) >> 16;
    ub = (ub + 0x7fffu + ((ub >> 16) & 1u)) >> 16;
    return (ub << 16) | ua;
}
__device__ __forceinline__ float bf_lo(unsigned d) { return __uint_as_float(d << 16); }
__device__ __forceinline__ float bf_hi(unsigned d) { return __uint_as_float(d & 0xffff0000u); }

// ---------------------------------------------------------------------------
// CSR build: count in-degree per dst
__global__ void count_k(const int* __restrict__ dst, int* __restrict__ counts) {
    int e = blockIdx.x * blockDim.x + threadIdx.x;
    if (e < N_EDGES) atomicAdd(&counts[dst[e]], 1);
}

// scan1: per-block sums of padded (x8) counts
__global__ __launch_bounds__(1024) void scan1_k(const int* __restrict__ counts,
                                                int* __restrict__ bsum) {
    __shared__ int s[1024];
    int i = blockIdx.x * 1024 + threadIdx.x;
    int c = 0;
    if (i < N_NODES) c = (counts[i] + 7) & ~7;
    s[threadIdx.x] = c;
    __syncthreads();
    for (int off = 512; off; off >>= 1) {
        if (threadIdx.x < off) s[threadIdx.x] += s[threadIdx.x + off];
        __syncthreads();
    }
    if (threadIdx.x == 0) bsum[blockIdx.x] = s[0];
}

// scan2: exclusive scan of the 98 block sums
__global__ void scan2_k(int* __restrict__ bsum) {
    __shared__ int s[128];
    int t = threadIdx.x;
    s[t] = (t < SCAN_BLOCKS) ? bsum[t] : 0;
    __syncthreads();
    for (int off = 1; off < 128; off <<= 1) {
        int v = (t >= off) ? s[t - off] : 0;
        __syncthreads();
        s[t] += v;
        __syncthreads();
    }
    if (t < SCAN_BLOCKS) bsum[t] = (t == 0) ? 0 : s[t - 1];
}

// scan3: per-block exclusive scan + block offset -> row_off / fill_pos
__global__ __launch_bounds__(1024) void scan3_k(const int* __restrict__ counts,
                                                const int* __restrict__ bsum,
                                                int* __restrict__ row_off,
                                                int* __restrict__ fill_pos) {
    __shared__ int s[1024];
    int i = blockIdx.x * 1024 + threadIdx.x;
    int c = 0;
    if (i < N_NODES) c = (counts[i] + 7) & ~7;
    s[threadIdx.x] = c;
    __syncthreads();
    for (int off = 1; off < 1024; off <<= 1) {
        int v = (threadIdx.x >= off) ? s[threadIdx.x - off] : 0;
        __syncthreads();
        s[threadIdx.x] += v;
        __syncthreads();
    }
    if (i <= N_NODES) {
        int excl = s[threadIdx.x] - c + bsum[blockIdx.x];
        row_off[i] = excl;
        fill_pos[i] = excl;
    }
}

// Bucket edges by dst; pack (src*64 [dword row offset], (1-alpha)*w fp32).
// Pad slots stay (0,0.0f) from the ep memset -> gather row 0 (cache-hot) * 0.
__global__ void bucket_k(const int* __restrict__ src, const int* __restrict__ dst,
                         const float* __restrict__ w,
                         int* __restrict__ fill_pos, int2* __restrict__ ep) {
    int e = blockIdx.x * blockDim.x + threadIdx.x;
    if (e >= N_EDGES) return;
    int d = dst[e];
    int pos = atomicAdd(&fill_pos[d], 1);
    float ws = (1.0f - ALPHA) * w[e];
    ep[pos] = make_int2(src[e] << 6, __float_as_int(ws));
}

// ---------------------------------------------------------------------------
// Encoder: H(bf16) = gelu(LN(x @ Wenc^T)).  (proven R5 structure)
__global__ __launch_bounds__(1024) void encoder_k(
        const float* __restrict__ x, const float* __restrict__ Wenc,
        const float* __restrict__ gamma, const float* __restrict__ beta,
        unsigned* __restrict__ H) {
    __shared__ float WT[IN_C * 130];
    __shared__ float XS[16][512];
    for (int i = threadIdx.x; i < IN_C * HID_C; i += 1024) {
        int c = i >> 7, k = i & 127;
        WT[k * 130 + c] = Wenc[i];
    }
    __syncthreads();
    int lane = threadIdx.x & 63;
    int wid  = threadIdx.x >> 6;
    const float2* WT2 = (const float2*)WT;
    float2 gb = ((const float2*)gamma)[lane];
    float2 bb = ((const float2*)beta)[lane];
    int wstride = gridDim.x * 16;
    float* xs = XS[wid];
    for (int grp = blockIdx.x * 16 + wid; grp * 4 < N_NODES; grp += wstride) {
        int r0 = grp * 4;
        const float4* xr = (const float4*)(x + (size_t)r0 * IN_C);
        ((float4*)xs)[lane]      = xr[lane];
        ((float4*)xs)[64 + lane] = xr[64 + lane];
        __builtin_amdgcn_wave_barrier();
        float a0x = 0, a0y = 0, a1x = 0, a1y = 0;
        float a2x = 0, a2y = 0, a3x = 0, a3y = 0;
        const float4* xs4 = (const float4*)xs;
#pragma unroll 4
        for (int k4 = 0; k4 < 32; ++k4) {
            float4 xv0 = xs4[k4];
            float4 xv1 = xs4[32 + k4];
            float4 xv2 = xs4[64 + k4];
            float4 xv3 = xs4[96 + k4];
            int k = k4 * 4;
            float2 w0 = WT2[(k + 0) * 65 + lane];
            float2 w1 = WT2[(k + 1) * 65 + lane];
            float2 w2 = WT2[(k + 2) * 65 + lane];
            float2 w3 = WT2[(k + 3) * 65 + lane];
#define ENC_ROW(ax, ay, xv)                                      \
            ax = fmaf(xv.x, w0.x, ax); ay = fmaf(xv.x, w0.y, ay); \
            ax = fmaf(xv.y, w1.x, ax); ay = fmaf(xv.y, w1.y, ay); \
            ax = fmaf(xv.z, w2.x, ax); ay = fmaf(xv.z, w2.y, ay); \
            ax = fmaf(xv.w, w3.x, ax); ay = fmaf(xv.w, w3.y, ay);
            ENC_ROW(a0x, a0y, xv0)
            ENC_ROW(a1x, a1y, xv1)
            ENC_ROW(a2x, a2y, xv2)
            ENC_ROW(a3x, a3y, xv3)
#undef ENC_ROW
        }
        __builtin_amdgcn_wave_barrier();
#define ENC_EPI(ax, ay, row)                                               \
        {                                                                   \
            float sum = ax + ay;                                            \
            for (int off = 32; off; off >>= 1) sum += __shfl_xor(sum, off); \
            float mu = sum * (1.0f / 128.0f);                               \
            float d0 = ax - mu, d1 = ay - mu;                               \
            float vs = d0 * d0 + d1 * d1;                                   \
            for (int off = 32; off; off >>= 1) vs += __shfl_xor(vs, off);   \
            float inv = rsqrtf(vs * (1.0f / 128.0f) + LN_EPS);              \
            float o0 = gelu_exact(gb.x * d0 * inv + bb.x);                  \
            float o1 = gelu_exact(gb.y * d1 * inv + bb.y);                  \
            H[(size_t)(row)*64 + lane] = pack_bf16_rne(o0, o1);             \
        }
        ENC_EPI(a0x, a0y, r0)
        ENC_EPI(a1x, a1y, r0 + 1)
        ENC_EPI(a2x, a2y, r0 + 2)
        ENC_EPI(a3x, a3y, r0 + 3)
#undef ENC_EPI
    }
}

// ---------------------------------------------------------------------------
// One APPNP step (pull), bf16. Wave per node; lane = channel pair (2l, 2l+1).
// 64-edge cooperative window; 16 row-gathers (256 B each) in flight in the
// main group, 8 in the tail (padded degree is a multiple of 8).
#define EDGE(J)                                                              \
    {                                                                         \
        int   o = __shfl(p.x, (J));                                           \
        float w = __int_as_float(__shfl(p.y, (J)));                           \
        unsigned dv = zin[o + lane];                                          \
        sx = fmaf(w, bf_lo(dv), sx); sy = fmaf(w, bf_hi(dv), sy);             \
    }
__global__ __launch_bounds__(256) void prop_k(
        const unsigned* __restrict__ zin, const unsigned* __restrict__ x0,
        const int* __restrict__ row_off, const int2* __restrict__ ep,
        unsigned* __restrict__ zout, int fuse_ln,
        const float* __restrict__ gamma, const float* __restrict__ beta) {
    int gw = (blockIdx.x * 256 + threadIdx.x) >> 6;   // node id
    if (gw >= N_NODES) return;
    int lane = threadIdx.x & 63;
    int s0 = row_off[gw];
    int s1 = row_off[gw + 1];                          // padded degree (x8)
    float sx = 0.f, sy = 0.f;
    for (int base = s0; base < s1; base += 64) {
        int cnt = min(64, s1 - base);                  // multiple of 8
        int2 p = make_int2(0, 0);
        if (lane < cnt) p = ep[base + lane];
        int j = 0;
        for (; j + 16 <= cnt; j += 16) {               // 16 gathers in flight
            int   o0 = __shfl(p.x, j + 0);  float w0 = __int_as_float(__shfl(p.y, j + 0));
            int   o1 = __shfl(p.x, j + 1);  float w1 = __int_as_float(__shfl(p.y, j + 1));
            int   o2 = __shfl(p.x, j + 2);  float w2 = __int_as_float(__shfl(p.y, j + 2));
            int   o3 = __shfl(p.x, j + 3);  float w3 = __int_as_float(__shfl(p.y, j + 3));
            int   o4 = __shfl(p.x, j + 4);  float w4 = __int_as_float(__shfl(p.y, j + 4));
            int   o5 = __shfl(p.x, j + 5);  float w5 = __int_as_float(__shfl(p.y, j + 5));
            int   o6 = __shfl(p.x, j + 6);  float w6 = __int_as_float(__shfl(p.y, j + 6));
            int   o7 = __shfl(p.x, j + 7);  float w7 = __int_as_float(__shfl(p.y, j + 7));
            int   o8 = __shfl(p.x, j + 8);  float w8 = __int_as_float(__shfl(p.y, j + 8));
            int   o9 = __shfl(p.x, j + 9);  float w9 = __int_as_float(__shfl(p.y, j + 9));
            int   oa = __shfl(p.x, j + 10); float wa = __int_as_float(__shfl(p.y, j + 10));
            int   ob = __shfl(p.x, j + 11); float wb = __int_as_float(__shfl(p.y, j + 11));
            int   oc = __shfl(p.x, j + 12); float wc = __int_as_float(__shfl(p.y, j + 12));
            int   od_ = __shfl(p.x, j + 13); float wd = __int_as_float(__shfl(p.y, j + 13));
            int   oe = __shfl(p.x, j + 14); float we = __int_as_float(__shfl(p.y, j + 14));
            int   of_ = __shfl(p.x, j + 15); float wf = __int_as_float(__shfl(p.y, j + 15));
            unsigned d0 = zin[o0 + lane];
            unsigned d1 = zin[o1 + lane];
            unsigned d2 = zin[o2 + lane];
            unsigned d3 = zin[o3 + lane];
            unsigned d4 = zin[o4 + lane];
            unsigned d5 = zin[o5 + lane];
            unsigned d6 = zin[o6 + lane];
            unsigned d7 = zin[o7 + lane];
            unsigned d8 = zin[o8 + lane];
            unsigned d9 = zin[o9 + lane];
            unsigned da = zin[oa + lane];
            unsigned db = zin[ob + lane];
            unsigned dc = zin[oc + lane];
            unsigned dd = zin[od_ + lane];
            unsigned de = zin[oe + lane];
            unsigned df = zin[of_ + lane];
            sx = fmaf(w0, bf_lo(d0), sx); sy = fmaf(w0, bf_hi(d0), sy);
            sx = fmaf(w1, bf_lo(d1), sx); sy = fmaf(w1, bf_hi(d1), sy);
            sx = fmaf(w2, bf_lo(d2), sx); sy = fmaf(w2, bf_hi(d2), sy);
            sx = fmaf(w3, bf_lo(d3), sx); sy = fmaf(w3, bf_hi(d3), sy);
            sx = fmaf(w4, bf_lo(d4), sx); sy = fmaf(w4, bf_hi(d4), sy);
            sx = fmaf(w5, bf_lo(d5), sx); sy = fmaf(w5, bf_hi(d5), sy);
            sx = fmaf(w6, bf_lo(d6), sx); sy = fmaf(w6, bf_hi(d6), sy);
            sx = fmaf(w7, bf_lo(d7), sx); sy = fmaf(w7, bf_hi(d7), sy);
            sx = fmaf(w8, bf_lo(d8), sx); sy = fmaf(w8, bf_hi(d8), sy);
            sx = fmaf(w9, bf_lo(d9), sx); sy = fmaf(w9, bf_hi(d9), sy);
            sx = fmaf(wa, bf_lo(da), sx); sy = fmaf(wa, bf_hi(da), sy);
            sx = fmaf(wb, bf_lo(db), sx); sy = fmaf(wb, bf_hi(db), sy);
            sx = fmaf(wc, bf_lo(dc), sx); sy = fmaf(wc, bf_hi(dc), sy);
            sx = fmaf(wd, bf_lo(dd), sx); sy = fmaf(wd, bf_hi(dd), sy);
            sx = fmaf(we, bf_lo(de), sx); sy = fmaf(we, bf_hi(de), sy);
            sx = fmaf(wf, bf_lo(df), sx); sy = fmaf(wf, bf_hi(df), sy);
        }
        if (j < cnt) {                                 // 8-edge tail
            int   o0 = __shfl(p.x, j + 0); float w0 = __int_as_float(__shfl(p.y, j + 0));
            int   o1 = __shfl(p.x, j + 1); float w1 = __int_as_float(__shfl(p.y, j + 1));
            int   o2 = __shfl(p.x, j + 2); float w2 = __int_as_float(__shfl(p.y, j + 2));
            int   o3 = __shfl(p.x, j + 3); float w3 = __int_as_float(__shfl(p.y, j + 3));
            int   o4 = __shfl(p.x, j + 4); float w4 = __int_as_float(__shfl(p.y, j + 4));
            int   o5 = __shfl(p.x, j + 5); float w5 = __int_as_float(__shfl(p.y, j + 5));
            int   o6 = __shfl(p.x, j + 6); float w6 = __int_as_float(__shfl(p.y, j + 6));
            int   o7 = __shfl(p.x, j + 7); float w7 = __int_as_float(__shfl(p.y, j + 7));
            unsigned d0 = zin[o0 + lane];
            unsigned d1 = zin[o1 + lane];
            unsigned d2 = zin[o2 + lane];
            unsigned d3 = zin[o3 + lane];
            unsigned d4 = zin[o4 + lane];
            unsigned d5 = zin[o5 + lane];
            unsigned d6 = zin[o6 + lane];
            unsigned d7 = zin[o7 + lane];
            sx = fmaf(w0, bf_lo(d0), sx); sy = fmaf(w0, bf_hi(d0), sy);
            sx = fmaf(w1, bf_lo(d1), sx); sy = fmaf(w1, bf_hi(d1), sy);
            sx = fmaf(w2, bf_lo(d2), sx); sy = fmaf(w2, bf_hi(d2), sy);
            sx = fmaf(w3, bf_lo(d3), sx); sy = fmaf(w3, bf_hi(d3), sy);
            sx = fmaf(w4, bf_lo(d4), sx); sy = fmaf(w4, bf_hi(d4), sy);
            sx = fmaf(w5, bf_lo(d5), sx); sy = fmaf(w5, bf_hi(d5), sy);
            sx = fmaf(w6, bf_lo(d6), sx); sy = fmaf(w6, bf_hi(d6), sy);
            sx = fmaf(w7, bf_lo(d7), sx); sy = fmaf(w7, bf_hi(d7), sy);
        }
    }
    unsigned xd = x0[(size_t)gw * 64 + lane];
    float zx = fmaf(ALPHA, bf_lo(xd), sx);
    float zy = fmaf(ALPHA, bf_hi(xd), sy);
    unsigned od;
    if (fuse_ln) {
        float h0 = gelu_exact(zx);
        float h1 = gelu_exact(zy);
        float sum = h0 + h1;
        for (int off = 32; off; off >>= 1) sum += __shfl_xor(sum, off);
        float mu = sum * (1.0f / 128.0f);
        float d0 = h0 - mu, d1 = h1 - mu;
        float vs = d0 * d0 + d1 * d1;
        for (int off = 32; off; off >>= 1) vs += __shfl_xor(vs, off);
        float inv = rsqrtf(vs * (1.0f / 128.0f) + LN_EPS);
        float2 gb = ((const float2*)gamma)[lane];
        float2 bb = ((const float2*)beta)[lane];
        od = pack_bf16_rne(gb.x * d0 * inv + bb.x, gb.y * d1 * inv + bb.y);
    } else {
        od = pack_bf16_rne(zx, zy);
    }
    zout[(size_t)gw * 64 + lane] = od;
}
#undef EDGE

// ---------------------------------------------------------------------------
// Decoder: out(fp32) = H(bf16) @ Wdec^T -> [N, 64].  (proven R5 structure)
__global__ __launch_bounds__(1024) void decoder_k(
        const unsigned* __restrict__ H, const float* __restrict__ Wdec,
        float* __restrict__ out) {
    __shared__ float WT[HID_C * 65];
    __shared__ unsigned XS[16][256];
    for (int i = threadIdx.x; i < OUT_C * HID_C; i += 1024) {
        int o = i >> 7, k = i & 127;
        WT[k * 65 + o] = Wdec[i];
    }
    __syncthreads();
    int lane = threadIdx.x & 63;
    int wid  = threadIdx.x >> 6;
    int wstride = gridDim.x * 16;
    unsigned* xs = XS[wid];
    for (int grp = blockIdx.x * 16 + wid; grp * 4 < N_NODES; grp += wstride) {
        int r0 = grp * 4;
        const unsigned* hp = H + (size_t)r0 * 64;
        xs[lane]       = hp[lane];
        xs[64 + lane]  = hp[64 + lane];
        xs[128 + lane] = hp[128 + lane];
        xs[192 + lane] = hp[192 + lane];
        __builtin_amdgcn_wave_barrier();
        float a0 = 0, a1 = 0, a2 = 0, a3 = 0;
#pragma unroll 4
        for (int k2 = 0; k2 < 64; ++k2) {
            float w0 = WT[(2 * k2) * 65 + lane];
            float w1 = WT[(2 * k2 + 1) * 65 + lane];
            unsigned u0 = xs[k2];
            unsigned u1 = xs[64 + k2];
            unsigned u2 = xs[128 + k2];
            unsigned u3 = xs[192 + k2];
            a0 = fmaf(bf_lo(u0), w0, a0); a0 = fmaf(bf_hi(u0), w1, a0);
            a1 = fmaf(bf_lo(u1), w0, a1); a1 = fmaf(bf_hi(u1), w1, a1);
            a2 = fmaf(bf_lo(u2), w0, a2); a2 = fmaf(bf_hi(u2), w1, a2);
            a3 = fmaf(bf_lo(u3), w0, a3); a3 = fmaf(bf_hi(u3), w1, a3);
        }
        __builtin_amdgcn_wave_barrier();
        out[(size_t)r0 * OUT_C + lane]       = a0;
        out[(size_t)(r0 + 1) * OUT_C + lane] = a1;
        out[(size_t)(r0 + 2) * OUT_C + lane] = a2;
        out[(size_t)(r0 + 3) * OUT_C + lane] = a3;
    }
}

// ---------------------------------------------------------------------------
extern "C" void kernel_launch(void* const* d_in, const int* in_sizes, int n_in,
                              void* d_out, int out_size, void* d_ws, size_t ws_size,
                              hipStream_t stream) {
    const float* x     = (const float*)d_in[0];
    const int*   ei    = (const int*)d_in[1];
    const float* ew    = (const float*)d_in[2];
    const float* Wenc  = (const float*)d_in[3];
    const float* Wdec  = (const float*)d_in[4];
    const float* gamma = (const float*)d_in[5];
    const float* beta  = (const float*)d_in[6];
    float* out = (float*)d_out;

    const int* src = ei;
    const int* dst = ei + N_EDGES;

    char* p = (char*)d_ws;
    auto carve = [&](size_t bytes) -> void* {
        void* r = (void*)p;
        p += (bytes + 255) & ~(size_t)255;
        return r;
    };
    int*  counts  = (int*)carve(SCAN_N * sizeof(int));
    int*  fillpos = (int*)carve(SCAN_N * sizeof(int));
    int*  row_off = (int*)carve(SCAN_N * sizeof(int));
    int*  bsum    = (int*)carve(SCAN_BLOCKS * sizeof(int));
    int2* ep      = (int2*)carve((size_t)EP_CAP * sizeof(int2));
    unsigned* H  = (unsigned*)carve((size_t)N_NODES * 64 * sizeof(unsigned));
    unsigned* ZA = (unsigned*)carve((size_t)N_NODES * 64 * sizeof(unsigned));
    unsigned* ZB = (unsigned*)carve((size_t)N_NODES * 64 * sizeof(unsigned));

    // CSR build (per launch; deterministic work each call)
    hipMemsetAsync(counts, 0, SCAN_N * sizeof(int), stream);
    hipMemsetAsync(ep, 0, (size_t)EP_CAP * sizeof(int2), stream);  // pads -> (0,0)
    count_k<<<(N_EDGES + 255) / 256, 256, 0, stream>>>(dst, counts);
    scan1_k<<<SCAN_BLOCKS, 1024, 0, stream>>>(counts, bsum);
    scan2_k<<<1, 128, 0, stream>>>(bsum);
    scan3_k<<<SCAN_BLOCKS, 1024, 0, stream>>>(counts, bsum, row_off, fillpos);
    bucket_k<<<(N_EDGES + 255) / 256, 256, 0, stream>>>(src, dst, ew, fillpos, ep);

    // Encoder
    encoder_k<<<512, 1024, 0, stream>>>(x, Wenc, gamma, beta, H);

    const int prop_blocks = (N_NODES + 3) / 4;   // 1 node/wave, 4 waves/block
    unsigned* bufs[2] = {ZA, ZB};
    for (int l = 0; l < NLAYERS; ++l) {
        const unsigned* zin = H;                  // x0 = H (layer input)
        for (int k = 0; k < KSTEPS; ++k) {
            int last = (k == KSTEPS - 1);
            unsigned* zout = last ? H : bufs[k & 1];
            prop_k<<<prop_blocks, 256, 0, stream>>>(zin, H, row_off, ep, zout,
                                                    last, gamma, beta);
            zin = zout;
        }
    }

    decoder_k<<<512, 1024, 0, stream>>>(H, Wdec, out);
}